// Round 17
// baseline (87.812 us; speedup 1.0000x reference)
//
#include <hip/hip_runtime.h>
#include <hip/hip_bf16.h>

#define NN 4096

typedef unsigned short u16;
typedef __attribute__((ext_vector_type(8))) short bf16x8;
typedef __attribute__((ext_vector_type(4))) float f32x4;

// fp32 -> bf16 round-to-nearest-even
static __device__ __forceinline__ u16 f2bf(float x) {
  unsigned u = __float_as_uint(x);
  u += 0x7fff + ((u >> 16) & 1);
  return (u16)(u >> 16);
}
static __device__ __forceinline__ float bf2f(u16 h) {
  return __uint_as_float((unsigned)h << 16);
}

// async global->LDS, 16B per lane; LDS dest = wave-uniform base + lane*16
static __device__ __forceinline__ void gload_lds16(const void* g, void* l) {
  __builtin_amdgcn_global_load_lds(
      (const __attribute__((address_space(1))) void*)g,
      (__attribute__((address_space(3))) void*)l, 16, 0, 0);
}

// ---------------------------------------------------------------------------
// Pass 1 (fused, grid 3200): R16 structure + ILP batching (convert was
// latency-bound: VALUBusy 5.7%, occupancy 46% -- batch loads before stores).
// ---------------------------------------------------------------------------
__global__ __launch_bounds__(256) void convert_fused(
    const float* __restrict__ A, const float* __restrict__ B,
    u16* __restrict__ Ab, u16* __restrict__ Bt) {
  __shared__ float t[64][65];
  const int blk = blockIdx.x;
  const int tid = threadIdx.x;

  if (blk < 1024) {  // ---- A path: 128x128 block (bi,kb) ----
    const int kb = blk & 31, bi = blk >> 5;
    const int rr = tid >> 5;
    if (kb > bi) {
      if (kb == bi + 1 && !(bi & 1)) {  // super-diagonal Ab: real zeros
        const ushort4 zz = {0, 0, 0, 0};
        const int c4b = (tid & 31) * 4;
#pragma unroll
        for (int p = 0; p < 16; ++p)
          *(ushort4*)&Ab[(long)(bi * 128 + p * 8 + rr) * NN + kb * 128 + c4b] =
              zz;
      }
      return;
    }
    const int c4 = (tid & 31) * 4;
    const bool diag = (kb == bi);
#pragma unroll
    for (int h = 0; h < 2; ++h) {
      float4 v[8];
#pragma unroll
      for (int p = 0; p < 8; ++p) {  // 8 loads in flight (ILP)
        const int row = (h * 8 + p) * 8 + rr;
        v[p] = *(const float4*)&A[(long)(bi * 128 + row) * NN + kb * 128 + c4];
      }
#pragma unroll
      for (int p = 0; p < 8; ++p) {
        const int row = (h * 8 + p) * 8 + rr;
        ushort4 o;
        if (diag) {
          const int i = bi * 128 + row, k = kb * 128 + c4;
          o.x = (k + 0 <= i) ? f2bf(v[p].x) : (u16)0;
          o.y = (k + 1 <= i) ? f2bf(v[p].y) : (u16)0;
          o.z = (k + 2 <= i) ? f2bf(v[p].z) : (u16)0;
          o.w = (k + 3 <= i) ? f2bf(v[p].w) : (u16)0;
        } else {
          o.x = f2bf(v[p].x); o.y = f2bf(v[p].y);
          o.z = f2bf(v[p].z); o.w = f2bf(v[p].w);
        }
        *(ushort4*)&Ab[(long)(bi * 128 + row) * NN + kb * 128 + c4] = o;
      }
    }
    return;
  }

  if (blk >= 3136) {  // ---- sub-diagonal Bt zero blocks ----
    const int idx = blk - 3136;  // 0..63
    const int q = idx >> 2;
    const int n0 = (2 * (2 * q + 1) + (idx & 1)) * 64;
    const int k0 = (2 * (2 * q) + ((idx >> 1) & 1)) * 64;
    const int n = tid >> 3;
    const int kc = (tid & 7) * 8;
    const uint4 z = {0u, 0u, 0u, 0u};
#pragma unroll
    for (int p = 0; p < 2; ++p)
      *(uint4*)&Bt[(long)(n0 + n + p * 32) * NN + k0 + kc] = z;
    return;
  }

  // ---- B path: pair-decoded 64x64 transpose tile ----
  const int t4 = blk - 1024;  // 0..2111
  int prem = t4 >> 2, N = 0;
  while (prem >= 32 - N) { prem -= 32 - N; ++N; }
  const int K = N + prem;  // N <= K
  const int sub = t4 & 3;
  const int n0 = (2 * N + (sub & 1)) * 64;
  const int k0 = (2 * K + (sub >> 1)) * 64;

  if (n0 > k0 + 63) {  // fully above diagonal -> zeros
    const int n = tid >> 3;
    const int kc = (tid & 7) * 8;
    const uint4 z = {0u, 0u, 0u, 0u};
#pragma unroll
    for (int p = 0; p < 2; ++p)
      *(uint4*)&Bt[(long)(n0 + n + p * 32) * NN + k0 + kc] = z;
    return;
  }

  float4 w[4];
#pragma unroll
  for (int p = 0; p < 4; ++p) {  // 4 loads in flight (ILP)
    const int r = (tid >> 4) + p * 16;
    w[p] = *(const float4*)&B[(long)(k0 + r) * NN + n0 + (tid & 15) * 4];
  }
#pragma unroll
  for (int p = 0; p < 4; ++p) {
    const int r = (tid >> 4) + p * 16;
    const int c = (tid & 15) * 4;
    const int kg = k0 + r;
    t[r][c + 0] = (n0 + c + 0 <= kg) ? w[p].x : 0.f;
    t[r][c + 1] = (n0 + c + 1 <= kg) ? w[p].y : 0.f;
    t[r][c + 2] = (n0 + c + 2 <= kg) ? w[p].z : 0.f;
    t[r][c + 3] = (n0 + c + 3 <= kg) ? w[p].w : 0.f;
  }
  __syncthreads();

#pragma unroll
  for (int p = 0; p < 2; ++p) {
    const int n = (tid >> 3) + p * 32;
    const int kc = (tid & 7) * 8;
    union { u16 h[8]; uint4 v; } pk;
#pragma unroll
    for (int j = 0; j < 8; ++j) pk.h[j] = f2bf(t[kc + j][n]);
    *(uint4*)&Bt[(long)(n0 + n) * NN + k0 + kc] = pk.v;
  }
}

// ---------------------------------------------------------------------------
// Pass 2: R16 gemm schedule with (a) equal-length chunks cc=ceil(4d/T) per
// tile (T=13 -> 316 items, max 13 steps ~= ideal 12.75 steps/CU) dispatched
// in GLOBAL LONGEST-FIRST order (decode iterates L=T..1, so late blocks are
// the shortest -> LPT makespan); (b) all 8 stage loads issued immediately
// after the step barrier (next step's vmcnt(0) finds them ~2.3us old >>
// HBM latency). Slabs: canonical (d,t,chunk) indexing. Zero-fill tail items
// (blocks >= nitems) unchanged.
// ---------------------------------------------------------------------------
template <int T>
__global__ __launch_bounds__(512, 2) void gemm_tril(
    const u16* __restrict__ Ab, const u16* __restrict__ Bt,
    float* __restrict__ C, u16* __restrict__ P, int nitems) {
  extern __shared__ u16 lds[];  // [2][16384] A | [2][16384] B = 128 KB
  u16* AsB = lds;
  u16* BsB = lds + 32768;

  const int tid = threadIdx.x;

  if ((int)blockIdx.x >= nitems) {  // ---- zero a strictly-upper 256-tile ----
    int zi = blockIdx.x - nitems;   // 0..119
    int bi = 0;
    for (; bi < 15; ++bi) {
      const int u = 15 - bi;
      if (zi < u) break;
      zi -= u;
    }
    const int bj = bi + 1 + zi;
    const float4 z = {0.f, 0.f, 0.f, 0.f};
#pragma unroll
    for (int p = 0; p < 32; ++p) {
      const int idx = p * 512 + tid;
      const int row = idx >> 6;
      const int col = (idx & 63) * 4;
      *(float4*)&C[(long)(bi * 256 + row) * NN + bj * 256 + col] = z;
    }
    return;
  }

  const int lane = tid & 63;
  const int wid = tid >> 6;  // 0..7
  const int wm = wid >> 2;   // 0..1 (128-row half)
  const int wn = wid & 3;    // 0..3 (64-col block)
  const int sm = lane >> 3;
  const int sks = ((lane & 7) ^ sm) * 8;  // pre-swizzled source col (u16)
  const int rsel = lane & 7;

  // ---- decode blockIdx.x in global longest-first order ----
  int rem = blockIdx.x;
  int d = 16, tt = 0, chunk = 0, cc = 1, ext = 0, base = 4, nk = 4;
  {
    bool found = false;
    for (int L = T; L >= 1 && !found; --L) {
      for (int dd = 16; dd >= 1; --dd) {
        const int n4 = 4 * dd;
        const int c2 = (n4 + T - 1) / T;  // compile-time T -> fast div
        const int b2 = n4 / c2, e2 = n4 % c2;
        const int cnt_hi = (L == b2 + 1) ? e2 : 0;
        const int cnt_lo = (L == b2) ? (c2 - e2) : 0;
        const int width = cnt_hi + cnt_lo;
        if (width == 0) continue;
        const int total = (17 - dd) * width;
        if (rem < total) {
          tt = rem / width;
          const int off = rem % width;
          chunk = (off < cnt_hi) ? off : e2 + (off - cnt_hi);
          d = dd; cc = c2; ext = e2; base = b2; nk = L;
          found = true;
          break;
        }
        rem -= total;
      }
    }
  }
  const int bi = d - 1 + tt;
  const int bj = tt;
  const int start = chunk * base + (chunk < ext ? chunk : ext);
  const int rA = bi * 256;
  const int rB = bj * 256;
  const long kbase = (long)bj * 256 + (long)start * 64;

  f32x4 acc[8][4];
#pragma unroll
  for (int i = 0; i < 8; ++i)
#pragma unroll
    for (int j = 0; j < 4; ++j) acc[i][j] = (f32x4){0.f, 0.f, 0.f, 0.f};

  // stage part c (of 4) of K64-step kt into buffer b: 2 gload_lds16
#define STAGE_PART(kt, b, c)                                               \
  do {                                                                     \
    const long k0 = kbase + (long)(kt)*64;                                 \
    const int ch = wid * 4 + (c);                                          \
    gload_lds16(Ab + ((long)(rA + ch * 8 + sm) * NN + k0 + sks),           \
                AsB + (b)*16384 + ch * 512);                               \
    gload_lds16(Bt + ((long)(rB + ch * 8 + sm) * NN + k0 + sks),           \
                BsB + (b)*16384 + ch * 512);                               \
  } while (0)

#pragma unroll
  for (int c = 0; c < 4; ++c) STAGE_PART(0, 0, c);

  for (int kt = 0; kt < nk; ++kt) {
    const int cur = kt & 1;
    asm volatile("s_waitcnt vmcnt(0)" ::: "memory");  // own stage landed
    __builtin_amdgcn_s_barrier();                     // all waves' stage done
    __builtin_amdgcn_sched_barrier(0);                // no read hoists above

    const u16* As = AsB + cur * 16384;
    const u16* Bs = BsB + cur * 16384;

    // issue ALL next-step stage loads up front: by the next vmcnt(0) they
    // are ~1 full step old (>> HBM latency) -> near-zero drain
    if (kt + 1 < nk) {
#pragma unroll
      for (int c = 0; c < 4; ++c) STAGE_PART(kt + 1, cur ^ 1, c);
    }

    // B fragments (whole step) + A fragments for phase 0
    bf16x8 bb[4][2];
#pragma unroll
    for (int n4 = 0; n4 < 4; ++n4)
#pragma unroll
      for (int kk = 0; kk < 2; ++kk) {
        const int fr = wn * 64 + n4 * 16 + (lane & 15);
        const int slot = ((kk * 4 + (lane >> 4)) ^ rsel) * 8;
        bb[n4][kk] = *(const bf16x8*)&Bs[fr * 64 + slot];
      }
    bf16x8 aa[2][2][2];  // [phase&1][mm][kk]
#pragma unroll
    for (int mm = 0; mm < 2; ++mm)
#pragma unroll
      for (int kk = 0; kk < 2; ++kk) {
        const int fr = wm * 128 + mm * 16 + (lane & 15);
        const int slot = ((kk * 4 + (lane >> 4)) ^ rsel) * 8;
        aa[0][mm][kk] = *(const bf16x8*)&As[fr * 64 + slot];
      }

#pragma unroll
    for (int p = 0; p < 4; ++p) {
      if (p < 3) {  // prefetch next phase's A fragments
#pragma unroll
        for (int mm = 0; mm < 2; ++mm)
#pragma unroll
          for (int kk = 0; kk < 2; ++kk) {
            const int fr = wm * 128 + (2 * (p + 1) + mm) * 16 + (lane & 15);
            const int slot = ((kk * 4 + (lane >> 4)) ^ rsel) * 8;
            aa[(p + 1) & 1][mm][kk] = *(const bf16x8*)&As[fr * 64 + slot];
          }
        asm volatile("s_waitcnt lgkmcnt(4)" ::: "memory");  // cur frags done
      } else {
        asm volatile("s_waitcnt lgkmcnt(0)" ::: "memory");
      }
      __builtin_amdgcn_sched_barrier(0);  // rule #18: no MFMA hoist past wait
      __builtin_amdgcn_s_setprio(1);
#pragma unroll
      for (int kk = 0; kk < 2; ++kk)
#pragma unroll
        for (int mm = 0; mm < 2; ++mm)
#pragma unroll
          for (int n4 = 0; n4 < 4; ++n4)
            acc[2 * p + mm][n4] = __builtin_amdgcn_mfma_f32_16x16x32_bf16(
                aa[p & 1][mm][kk], bb[n4][kk], acc[2 * p + mm][n4], 0, 0, 0);
      __builtin_amdgcn_s_setprio(0);
    }
  }
#undef STAGE_PART

  // ---- epilogue: C/D layout col=lane&15, row=(lane>>4)*4+r ----
  const int lrow = wm * 128 + (lane >> 4) * 4;
  const int lcol = wn * 64 + (lane & 15);
  if (chunk == 0) {
    const bool diag = (bi == bj);
#pragma unroll
    for (int m4 = 0; m4 < 8; ++m4)
#pragma unroll
      for (int n4 = 0; n4 < 4; ++n4)
#pragma unroll
        for (int r = 0; r < 4; ++r) {
          const int gi = rA + lrow + m4 * 16 + r;
          const int gj = rB + lcol + n4 * 16;
          float v = acc[m4][n4][r];
          if (diag && gj > gi) v = 0.f;
          C[(long)gi * NN + gj] = v;
        }
  } else {
    // canonical slab index: pre(d) + t*(cc-1) + chunk-1
    int pre = 0;
    for (int dd = 16; dd > d; --dd) {
      const int c2 = (4 * dd + T - 1) / T;
      pre += (17 - dd) * (c2 - 1);
    }
    u16* slab = P + (long)(pre + tt * (cc - 1) + chunk - 1) * 65536;
#pragma unroll
    for (int m4 = 0; m4 < 8; ++m4)
#pragma unroll
      for (int n4 = 0; n4 < 4; ++n4)
#pragma unroll
        for (int r = 0; r < 4; ++r)
          slab[(lrow + m4 * 16 + r) * 256 + lcol + n4 * 16] =
              f2bf(acc[m4][n4][r]);
  }
}

// ---------------------------------------------------------------------------
// Pass 3: add bf16 partial slabs into C for tiles with cc>=2 (d > T/4),
// 4 row-stripes per tile.
// ---------------------------------------------------------------------------
template <int T>
__global__ __launch_bounds__(256) void reduce_partials(
    float* __restrict__ C, const u16* __restrict__ P) {
  int rem = blockIdx.x >> 2;
  const int stripe = blockIdx.x & 3;

  int d = 16, tt = 0, cc = 1, slabpre = 0;
  {
    bool found = false;
    for (int dd = 16; dd >= 1 && !found; --dd) {
      const int c2 = (4 * dd + T - 1) / T;
      if (c2 >= 2) {
        const int cnt = 17 - dd;
        if (rem < cnt) {
          d = dd; tt = rem; cc = c2;
          found = true;
          break;
        }
        rem -= cnt;
      }
      slabpre += (17 - dd) * (c2 - 1);
    }
    if (!found) return;
  }
  const int bi = d - 1 + tt;
  const int bj = tt;
  const int slaboff = slabpre + tt * (cc - 1);

  const int tid = threadIdx.x;
#pragma unroll
  for (int p = 0; p < 16; ++p) {
    const int idx = p * 256 + tid;  // 4096 float4 per 64-row stripe
    const int row = stripe * 64 + (idx >> 6);
    const int col = (idx & 63) * 4;
    const long coff = (long)(bi * 256 + row) * NN + bj * 256 + col;
    float4 acc = *(const float4*)&C[coff];
    for (int e = 0; e < cc - 1; ++e) {
      const ushort4 q =
          *(const ushort4*)&P[(long)(slaboff + e) * 65536 + row * 256 + col];
      acc.x += bf2f(q.x); acc.y += bf2f(q.y);
      acc.z += bf2f(q.z); acc.w += bf2f(q.w);
    }
    *(float4*)&C[coff] = acc;
  }
}

// ---------------------------------------------------------------------------
// Fallback (ws too small): naive fp32.
// ---------------------------------------------------------------------------
__global__ void naive_tril(const float* __restrict__ A,
                           const float* __restrict__ B, float* __restrict__ C) {
  const int j = blockIdx.x * 256 + threadIdx.x;
  const int i = blockIdx.y;
  float s = 0.f;
  for (int k = j; k <= i; ++k) s += A[(long)i * NN + k] * B[(long)k * NN + j];
  C[(long)i * NN + j] = s;
}

extern "C" void kernel_launch(void* const* d_in, const int* in_sizes, int n_in,
                              void* d_out, int out_size, void* d_ws,
                              size_t ws_size, hipStream_t stream) {
  const float* A = (const float*)d_in[0];
  const float* B = (const float*)d_in[1];
  float* C = (float*)d_out;

  const size_t opbytes = (size_t)2 * NN * NN * sizeof(u16);  // 64 MB operands
  const size_t slab = 131072;  // 256x256 bf16
  // tiers: T=13 -> 316 items / 180 slabs (22.5 MB) / 91 reduce tiles
  //        T=52 -> 142 items /   6 slabs          /  6 reduce tiles
  const size_t need13 = opbytes + 180 * slab;  // 86.5 MiB (ws>=107 proven R13)
  const size_t need52 = opbytes + 6 * slab;

  if (ws_size < opbytes) {
    naive_tril<<<dim3(16, NN), 256, 0, stream>>>(A, B, C);
    return;
  }

  u16* Ab = (u16*)d_ws;
  u16* Bt = Ab + (long)NN * NN;
  u16* P = (u16*)((char*)d_ws + opbytes);

  convert_fused<<<3200, 256, 0, stream>>>(A, B, Ab, Bt);

  if (ws_size >= need13) {
    hipFuncSetAttribute((const void*)gemm_tril<13>,
                        hipFuncAttributeMaxDynamicSharedMemorySize, 131072);
    gemm_tril<13><<<316 + 120, 512, 131072, stream>>>(Ab, Bt, C, P, 316);
    reduce_partials<13><<<91 * 4, 256, 0, stream>>>(C, P);
  } else if (ws_size >= need52) {
    hipFuncSetAttribute((const void*)gemm_tril<52>,
                        hipFuncAttributeMaxDynamicSharedMemorySize, 131072);
    gemm_tril<52><<<142 + 120, 512, 131072, stream>>>(Ab, Bt, C, P, 142);
    reduce_partials<52><<<6 * 4, 256, 0, stream>>>(C, P);
  } else {
    hipFuncSetAttribute((const void*)gemm_tril<64>,
                        hipFuncAttributeMaxDynamicSharedMemorySize, 131072);
    gemm_tril<64><<<136 + 120, 512, 131072, stream>>>(Ab, Bt, C, P, 136);
    // T=64: every tile single-chunk -> no slabs, no reduce
  }
}